// Round 9
// baseline (147.218 us; speedup 1.0000x reference)
//
#include <hip/hip_runtime.h>
#include <hip/hip_bf16.h>

#define T_STEPS 128
#define BATCH   2048
#define IN_F    64
#define HID     256
#define OUT_F   16
#define CH      8                  // timesteps per P-exchange group
#define TROWS   16                 // batch rows per block
#define HQ      64                 // hid columns per block (4 waves x 16)
#define NCH     (T_STEPS / CH)     // 16 groups
#define SLAB    (BATCH * OUT_F)
#define PD      4                  // x register-prefetch distance (steps)

typedef __attribute__((ext_vector_type(8))) short bf16x8;
typedef __attribute__((ext_vector_type(4))) float f32x4;
typedef unsigned short u16;
typedef unsigned int   u32;

__device__ __forceinline__ u16 f2bf(float f) {      // RNE via HW cvt (pk-fusable)
    union { __hip_bfloat16 h; u16 u; } cv;
    cv.h = __float2bfloat16(f);
    return cv.u;
}
__device__ __forceinline__ float bf2f(u16 h) {
    return __uint_as_float(((u32)h) << 16);
}
__device__ __forceinline__ bf16x8 pack8(float4 a, float4 b) {
    bf16x8 r;
    r[0] = (short)f2bf(a.x); r[1] = (short)f2bf(a.y);
    r[2] = (short)f2bf(a.z); r[3] = (short)f2bf(a.w);
    r[4] = (short)f2bf(b.x); r[5] = (short)f2bf(b.y);
    r[6] = (short)f2bf(b.z); r[7] = (short)f2bf(b.w);
    return r;
}

// Zero the spikes_mean accumulator (d_out not re-poisoned between replays).
__global__ void snn_init_kernel(float* __restrict__ out) {
    if (threadIdx.x == 0 && blockIdx.x == 0) out[BATCH * OUT_F] = 0.0f;
}

// Kernel 1: transposed-layer-1 LIF. Block = 16 rows x 64 hid (4 waves x 16
// hid), grid 512 -> 2 blocks/CU, 8 waves/CU. z never leaves its lane: G1^T
// C-layout (row=l15, hid=4hi+r) IS layer-2's A-frag slot (m=l15, k=8hi+i),
// zero-padded to K=32. LDS only for the per-step P-partial exchange.
__global__ void __launch_bounds__(256, 2)
snn_l1_kernel(const float* __restrict__ x, const float* __restrict__ w1,
              const float* __restrict__ w2, u16* __restrict__ g2p,
              float* __restrict__ out)
{
    const int tid  = threadIdx.x;
    const int lane = tid & 63;
    const int wv   = tid >> 6;               // 4 waves; wave owns 16 hid
    const int hi   = lane >> 4;
    const int l15  = lane & 15;              // batch row within tile
    const int tile = blockIdx.x & 127;       // quarters of a tile: same XCD
    const int q    = blockIdx.x >> 7;        // hid quarter
    const int row0 = tile * TROWS;
    const int hbase = q * HQ + wv * 16;      // this wave's 16 hid

    __shared__ __attribute__((aligned(16))) float ws[2][CH][4][256];  // 64 KB
    __shared__ float sacc;
    if (tid == 0) sacc = 0.f;

    const f32x4 zf = {0.f, 0.f, 0.f, 0.f};
    const float dt_tau = (float)(0.001 * (1.0 / 0.006));       // 1/6
    const float decay  = (float)(1.0 - 0.001 * (1.0 / 0.006)); // 5/6

    // W1 as MFMA A-frags: A[n=hid][k=in]; lane: n = l15, k = 32kh + 8hi + i.
    bf16x8 w1f[2];
#pragma unroll
    for (int kh = 0; kh < 2; ++kh) {
        const float* src = &w1[(hbase + l15) * IN_F + kh * 32 + hi * 8];
        w1f[kh] = pack8(*(const float4*)src, *(const float4*)(src + 4));
    }

    // W2 as layer-2 B-frag, K=32 with slots (hi, i<4) <-> hid hbase+4hi+i,
    // slots i>=4 zero (matching zero A slots -> contribute 0).
    bf16x8 w2f;
#pragma unroll
    for (int i = 0; i < 8; ++i)
        w2f[i] = (i < 4) ? (short)f2bf(w2[l15 * HID + hbase + 4 * hi + i])
                         : (short)0;

    // Rolling x prefetch: slot j holds step t (t mod 4 == j; j = s&3 is
    // compile-time in the unrolled body -> static register indexing).
    // Per lane (B-frag x^T: col m = l15 -> row row0+l15; k = 32kh+8hi+i):
    // floats [8hi, 8hi+8) and [32+8hi, 32+8hi+8) of that row.
    const size_t tstride = (size_t)BATCH * IN_F;
    const float* xp[PD];
    float4 ra[PD], rb[PD], rc[PD], rd[PD];
#pragma unroll
    for (int j = 0; j < PD; ++j) {
        xp[j] = x + (size_t)j * tstride + (row0 + l15) * IN_F + hi * 8;
        ra[j] = *(const float4*)(xp[j]);
        rb[j] = *(const float4*)(xp[j] + 4);
        rc[j] = *(const float4*)(xp[j] + 32);
        rd[j] = *(const float4*)(xp[j] + 36);
    }

    f32x4 v1 = zf, i1 = zf;
    int wcnt = 0;
    int pb = 0;
    __syncthreads();

    for (int c = 0; c < NCH; ++c) {
#pragma unroll
        for (int s = 0; s < CH; ++s) {
            const int j = s & (PD - 1);            // compile-time

            // pack this step's x B-frags from prefetched regs
            const bf16x8 xf0 = pack8(ra[j], rb[j]);
            const bf16x8 xf1 = pack8(rc[j], rd[j]);

            // refill slot j with step t+PD (issue loads early)
            if ((s < PD) || (c + 1 < NCH)) {       // s<PD: compile-time true
                xp[j] += PD * tstride;
                ra[j] = *(const float4*)(xp[j]);
                rb[j] = *(const float4*)(xp[j] + 4);
                rc[j] = *(const float4*)(xp[j] + 32);
                rd[j] = *(const float4*)(xp[j] + 36);
            }

            // layer 1 (transposed): D[n=hid][m=row]; lane: m=l15, n=4hi+r
            f32x4 g1 = __builtin_amdgcn_mfma_f32_16x16x32_bf16(w1f[0], xf0, zf, 0, 0, 0);
            g1 = __builtin_amdgcn_mfma_f32_16x16x32_bf16(w1f[1], xf1, g1, 0, 0, 0);

            // LIF: state is 4 hid values of row l15; z stays in-lane
            const f32x4 vd = v1 + dt_tau * (i1 - v1);
            bool sp[4];
#pragma unroll
            for (int r = 0; r < 4; ++r) {
                sp[r] = vd[r] > 1.0f;
                v1[r] = sp[r] ? 0.f : vd[r];
                wcnt += __popcll(__ballot(sp[r]));
            }
            i1 = i1 * decay + g1;

            union { u32 u[4]; bf16x8 v; } zz;
            zz.u[0] = (sp[0] ? 0x3F80u : 0u) | (sp[1] ? 0x3F800000u : 0u);
            zz.u[1] = (sp[2] ? 0x3F80u : 0u) | (sp[3] ? 0x3F800000u : 0u);
            zz.u[2] = 0u; zz.u[3] = 0u;

            // layer-2 partial over this wave's 16 hid (K=32, half zero)
            const f32x4 p = __builtin_amdgcn_mfma_f32_16x16x32_bf16(zz.v, w2f, zf, 0, 0, 0);
            *(f32x4*)&ws[pb][s][wv][lane * 4] = p;
        }

        __syncthreads();   // one barrier per 8 steps

        // reduce: wave wv sums 4 waves' partials for steps 2wv, 2wv+1;
        // next group's producers write ws[pb^1] -> no race with these reads.
#pragma unroll
        for (int q2 = 0; q2 < 2; ++q2) {
            const int s = wv * 2 + q2;
            const float* wp = &ws[pb][s][0][lane * 4];
            const f32x4 a0 = *(const f32x4*)(wp);
            const f32x4 a1 = *(const f32x4*)(wp + 256);
            const f32x4 a2 = *(const f32x4*)(wp + 512);
            const f32x4 a3 = *(const f32x4*)(wp + 768);
            const f32x4 g2 = (a0 + a1) + (a2 + a3);
            // P layout: lane (hi,l15) holds rows 4hi+r, out col l15
            u16* dst = g2p + (size_t)q * (T_STEPS * SLAB)
                     + (size_t)(c * CH + s) * SLAB + (row0 + 4 * hi) * OUT_F + l15;
#pragma unroll
            for (int r = 0; r < 4; ++r) dst[r * OUT_F] = f2bf(g2[r]);
        }
        pb ^= 1;
    }

    // spikes: wcnt is wave-uniform -> one LDS atomic per wave, one global atomic
    if (lane == 0) atomicAdd(&sacc, (float)wcnt);
    __syncthreads();
    if (tid == 0) atomicAdd(&out[BATCH * OUT_F], sacc * (1.0f / BATCH));
}

// Kernel 2: LI recurrence + max over t; one thread per (row, out) chain;
// sums the 4 quarter-slabs.
__global__ void __launch_bounds__(256)
snn_li_kernel(const u16* __restrict__ g2p, float* __restrict__ out)
{
    const int gid = blockIdx.x * 256 + threadIdx.x;    // 0..32767
    const u16* p0 = g2p + gid;
    const u16* p1 = p0 + (size_t)T_STEPS * SLAB;
    const u16* p2 = p1 + (size_t)T_STEPS * SLAB;
    const u16* p3 = p2 + (size_t)T_STEPS * SLAB;
    const float dt_tau = (float)(0.001 * (1.0 / 0.006));
    const float decay  = (float)(1.0 - 0.001 * (1.0 / 0.006));
    float v2 = 0.f, i2 = 0.f, ymax = -1e30f;
#pragma unroll 8
    for (int t = 0; t < T_STEPS; ++t) {
        const size_t o = (size_t)t * SLAB;
        const float g = (bf2f(p0[o]) + bf2f(p1[o])) + (bf2f(p2[o]) + bf2f(p3[o]));
        v2 = fmaf(dt_tau, i2 - v2, v2);   // uses old i2, matches reference
        ymax = fmaxf(ymax, v2);
        i2 = i2 * decay + g;
    }
    out[gid] = ymax;
}

extern "C" void kernel_launch(void* const* d_in, const int* in_sizes, int n_in,
                              void* d_out, int out_size, void* d_ws, size_t ws_size,
                              hipStream_t stream) {
    const float* x  = (const float*)d_in[0];
    const float* w1 = (const float*)d_in[1];
    const float* w2 = (const float*)d_in[2];
    float* out = (float*)d_out;
    u16* g2p = (u16*)d_ws;   // 4 quarters x 128 t x 32768 bf16 = 32 MB

    hipLaunchKernelGGL(snn_init_kernel, dim3(1), dim3(64), 0, stream, out);
    hipLaunchKernelGGL(snn_l1_kernel, dim3(512), dim3(256), 0, stream,
                       x, w1, w2, g2p, out);
    hipLaunchKernelGGL(snn_li_kernel, dim3(BATCH * OUT_F / 256), dim3(256), 0,
                       stream, g2p, out);
}

// Round 10
// 62.219 us; speedup vs baseline: 2.3661x; 2.3661x over previous
//
#include <hip/hip_runtime.h>
#include <hip/hip_bf16.h>

#define T_STEPS 128
#define BATCH   2048
#define IN_F    64
#define HID     256
#define OUT_F   16
#define CH      16                 // timesteps per staged x chunk
#define GRP     8                  // timesteps per P-reduce group
#define NCH     (T_STEPS / CH)     // 8 chunks
#define SLAB    (BATCH * OUT_F)

typedef __attribute__((ext_vector_type(8))) short bf16x8;
typedef __attribute__((ext_vector_type(4))) float f32x4;
typedef unsigned short u16;
typedef unsigned int   u32;

__device__ __forceinline__ u16 f2bf(float f) {      // RNE via HW cvt (pk-fusable)
    union { __hip_bfloat16 h; u16 u; } cv;
    cv.h = __float2bfloat16(f);
    return cv.u;
}
__device__ __forceinline__ float bf2f(u16 h) {
    return __uint_as_float(((u32)h) << 16);
}
__device__ __forceinline__ bf16x8 pack8(float4 a, float4 b) {
    bf16x8 r;
    r[0] = (short)f2bf(a.x); r[1] = (short)f2bf(a.y);
    r[2] = (short)f2bf(a.z); r[3] = (short)f2bf(a.w);
    r[4] = (short)f2bf(b.x); r[5] = (short)f2bf(b.y);
    r[6] = (short)f2bf(b.z); r[7] = (short)f2bf(b.w);
    return r;
}

// Zero the spikes_mean accumulator (d_out not re-poisoned between replays).
__global__ void snn_init_kernel(float* __restrict__ out) {
    if (threadIdx.x == 0 && blockIdx.x == 0) out[BATCH * OUT_F] = 0.0f;
}

// Kernel 1: hybrid. Block = 16 rows x 128 hid, 8 waves (wave = 16 hid).
// x: LDS-staged bf16 in fragment order (stride-1 ds_read_b128 per operand);
// z: registers only (transposed-MFMA layout chain, verified R8/R9);
// P partials: bf16x4 -> double-buffered ws, ONE barrier per 8 steps.
__global__ void __launch_bounds__(512, 2)
snn_l1_kernel(const float* __restrict__ x, const float* __restrict__ w1,
              const float* __restrict__ w2, u16* __restrict__ g2p,
              float* __restrict__ out)
{
    const int tid  = threadIdx.x;
    const int lane = tid & 63;
    const int wv   = tid >> 6;               // 8 waves; wave owns 16 hid
    const int hi   = lane >> 4;
    const int l15  = lane & 15;              // batch row within tile
    const int tile = blockIdx.x & 127;       // halves of a tile: same XCD
    const int half = blockIdx.x >> 7;
    const int row0 = tile * 16;
    const int hbase = half * 128 + wv * 16;  // this wave's 16 hid

    // x frags: [buf][step][frag(2)][lane*8 bf16] -> 16B per lane, stride-1
    __shared__ __attribute__((aligned(16))) u16 xl[2][CH * 2 * 512];     // 64 KB
    // P partials: [buf][step-in-grp][wave][lane*2 u32] (bf16x4 per lane)
    __shared__ __attribute__((aligned(16))) u32 ws[2][GRP][8][128];      // 64 KB
    __shared__ float sacc;
    if (tid == 0) sacc = 0.f;

    const f32x4 zf = {0.f, 0.f, 0.f, 0.f};
    const float dt_tau = (float)(0.001 * (1.0 / 0.006));       // 1/6
    const float decay  = (float)(1.0 - 0.001 * (1.0 / 0.006)); // 5/6

    // W1 as MFMA A-frags: A[n=hid][k=in]; lane: n = l15, k = 32kh + 8hi + i.
    bf16x8 w1f[2];
#pragma unroll
    for (int kh = 0; kh < 2; ++kh) {
        const float* src = &w1[(hbase + l15) * IN_F + kh * 32 + hi * 8];
        w1f[kh] = pack8(*(const float4*)src, *(const float4*)(src + 4));
    }
    // W2 as layer-2 B-frag, K=32 half-zero (slots i<4 <-> hid hbase+4hi+i).
    bf16x8 w2f;
#pragma unroll
    for (int i = 0; i < 8; ++i)
        w2f[i] = (i < 4) ? (short)f2bf(w2[l15 * HID + hbase + 4 * hi + i])
                         : (short)0;

    // ---- x staging map: 2048 16B-units per chunk, 4 per thread ----
    // unit u: s = u>>7; r7 = u&127: f = r7>>6, chi = (r7>>4)&3, cl = r7&15
    // holds bf16 of x[t0+s][row0+cl][32f + 8*chi .. +8]
    const size_t cstride = (size_t)CH * BATCH * IN_F;
    const float* gp[4];
    int wofs[4];
#pragma unroll
    for (int j = 0; j < 4; ++j) {
        const int u  = tid + 512 * j;
        const int s  = u >> 7, r7 = u & 127;
        const int f  = r7 >> 6, chi = (r7 >> 4) & 3, cl = r7 & 15;
        wofs[j] = (s * 2 + f) * 512 + (chi * 16 + cl) * 8;   // u16 index
        gp[j]   = x + ((size_t)s * BATCH + row0 + cl) * IN_F + f * 32 + chi * 8;
    }
    // prologue: chunk 0 -> LDS; chunk 1 -> regs (T14 split); gp -> chunk 2
    float4 ra[4], rb[4];
#pragma unroll
    for (int j = 0; j < 4; ++j) {
        ra[j] = *(const float4*)gp[j];
        rb[j] = *(const float4*)(gp[j] + 4);
        *(bf16x8*)&xl[0][wofs[j]] = pack8(ra[j], rb[j]);
    }
#pragma unroll
    for (int j = 0; j < 4; ++j) {
        ra[j] = *(const float4*)(gp[j] + cstride);
        rb[j] = *(const float4*)(gp[j] + cstride + 4);
        gp[j] += 2 * cstride;
    }

    f32x4 v1 = zf, i1 = zf;
    int wcnt = 0;
    __syncthreads();

    for (int c = 0; c < NCH; ++c) {
        const int cb = c & 1;
        const u16* xb = &xl[cb][0];

        // stage chunk c+1 from regs (dead buffer); issue loads for c+2
        if (c + 1 < NCH) {
#pragma unroll
            for (int j = 0; j < 4; ++j)
                *(bf16x8*)&xl[cb ^ 1][wofs[j]] = pack8(ra[j], rb[j]);
        }
        if (c + 2 < NCH) {
#pragma unroll
            for (int j = 0; j < 4; ++j) {
                ra[j] = *(const float4*)gp[j];
                rb[j] = *(const float4*)(gp[j] + 4);
                gp[j] += cstride;
            }
        }

#pragma unroll
        for (int g = 0; g < 2; ++g) {
            const int pb = (c * 2 + g) & 1;
#pragma unroll
            for (int ss = 0; ss < GRP; ++ss) {
                const int s = g * GRP + ss;
                // stride-1, conflict-free 16B reads
                const bf16x8 xf0 = *(const bf16x8*)&xb[(s * 2 + 0) * 512 + lane * 8];
                const bf16x8 xf1 = *(const bf16x8*)&xb[(s * 2 + 1) * 512 + lane * 8];

                // layer 1 (transposed): lane holds rows n = 4hi+r, col m = l15
                f32x4 g1 = __builtin_amdgcn_mfma_f32_16x16x32_bf16(w1f[0], xf0, zf, 0, 0, 0);
                g1 = __builtin_amdgcn_mfma_f32_16x16x32_bf16(w1f[1], xf1, g1, 0, 0, 0);

                // LIF: 4 hid of row l15; z stays in-lane
                const f32x4 vd = v1 + dt_tau * (i1 - v1);
                bool sp[4];
#pragma unroll
                for (int r = 0; r < 4; ++r) {
                    sp[r] = vd[r] > 1.0f;
                    v1[r] = sp[r] ? 0.f : vd[r];
                    wcnt += __popcll(__ballot(sp[r]));
                }
                i1 = i1 * decay + g1;

                union { u32 u[4]; bf16x8 v; } zz;
                zz.u[0] = (sp[0] ? 0x3F80u : 0u) | (sp[1] ? 0x3F800000u : 0u);
                zz.u[1] = (sp[2] ? 0x3F80u : 0u) | (sp[3] ? 0x3F800000u : 0u);
                zz.u[2] = 0u; zz.u[3] = 0u;

                // layer-2 partial over this wave's 16 hid (K=32 half-zero)
                const f32x4 p = __builtin_amdgcn_mfma_f32_16x16x32_bf16(zz.v, w2f, zf, 0, 0, 0);
                uint2 pw;
                pw.x = (u32)f2bf(p[0]) | ((u32)f2bf(p[1]) << 16);
                pw.y = (u32)f2bf(p[2]) | ((u32)f2bf(p[3]) << 16);
                *(uint2*)&ws[pb][ss][wv][lane * 2] = pw;
            }

            __syncthreads();   // one barrier per 8 steps

            // reduce: wave wv sums 8 waves' partials for step g*8+wv;
            // producers of the next group write ws[pb^1] -> no race.
            {
                f32x4 acc = zf;
#pragma unroll
                for (int w = 0; w < 8; ++w) {
                    const uint2 pw = *(const uint2*)&ws[pb][wv][w][lane * 2];
                    acc[0] += __uint_as_float(pw.x << 16);
                    acc[1] += __uint_as_float(pw.x & 0xFFFF0000u);
                    acc[2] += __uint_as_float(pw.y << 16);
                    acc[3] += __uint_as_float(pw.y & 0xFFFF0000u);
                }
                const int t = c * CH + g * GRP + wv;
                u16* dst = g2p + (size_t)half * (T_STEPS * SLAB)
                         + (size_t)t * SLAB + (row0 + 4 * hi) * OUT_F + l15;
#pragma unroll
                for (int r = 0; r < 4; ++r) dst[r * OUT_F] = f2bf(acc[r]);
            }
        }
    }

    // spikes: wcnt is wave-uniform -> one LDS atomic per wave, one global atomic
    if (lane == 0) atomicAdd(&sacc, (float)wcnt);
    __syncthreads();
    if (tid == 0) atomicAdd(&out[BATCH * OUT_F], sacc * (1.0f / BATCH));
}

// Kernel 2: LI recurrence + max over t; one thread per (row, out) chain;
// sums the 2 half-slabs.
__global__ void __launch_bounds__(256)
snn_li_kernel(const u16* __restrict__ g2p, float* __restrict__ out)
{
    const int gid = blockIdx.x * 256 + threadIdx.x;    // 0..32767
    const u16* p0 = g2p + gid;
    const u16* p1 = p0 + (size_t)T_STEPS * SLAB;
    const float dt_tau = (float)(0.001 * (1.0 / 0.006));
    const float decay  = (float)(1.0 - 0.001 * (1.0 / 0.006));
    float v2 = 0.f, i2 = 0.f, ymax = -1e30f;
#pragma unroll 8
    for (int t = 0; t < T_STEPS; ++t) {
        const size_t o = (size_t)t * SLAB;
        const float g = bf2f(p0[o]) + bf2f(p1[o]);
        v2 = fmaf(dt_tau, i2 - v2, v2);   // uses old i2, matches reference
        ymax = fmaxf(ymax, v2);
        i2 = i2 * decay + g;
    }
    out[gid] = ymax;
}

extern "C" void kernel_launch(void* const* d_in, const int* in_sizes, int n_in,
                              void* d_out, int out_size, void* d_ws, size_t ws_size,
                              hipStream_t stream) {
    const float* x  = (const float*)d_in[0];
    const float* w1 = (const float*)d_in[1];
    const float* w2 = (const float*)d_in[2];
    float* out = (float*)d_out;
    u16* g2p = (u16*)d_ws;   // 2 halves x 128 t x 32768 bf16 = 16 MB

    hipLaunchKernelGGL(snn_init_kernel, dim3(1), dim3(64), 0, stream, out);
    hipLaunchKernelGGL(snn_l1_kernel, dim3(256), dim3(512), 0, stream,
                       x, w1, w2, g2p, out);
    hipLaunchKernelGGL(snn_li_kernel, dim3(BATCH * OUT_F / 256), dim3(256), 0,
                       stream, g2p, out);
}